// Round 11
// baseline (166.412 us; speedup 1.0000x reference)
//
#include <hip/hip_runtime.h>
#include <hip/hip_fp16.h>

// B=256 queries, D=2048, d=64 hash dim, N=100000 database, C=100 classes,
// K=1000 SMALLEST-sim selection. Inputs f32, labels int, output f32.
//
// R17: two-level classify skip. mhist emits gmin[row][group] = min bucket of
// each 16-code group (4-step width-16 shfl_xor min — the 16 buckets already
// live in 16 lanes of one wave). rowfinal scans gmin (6.25KB/row) with the
// hasless gate and touches buck (16B) only for flagged groups (~2% of codes
// are below/cand; same exact sets). Dots loop 2-deep unrolled. prep unchanged.
//   k_prep    : detect + codes f32->f16 (+max||c||^2 slab) + out=x@W f64/f16
//   k_mhist   : MFMA screen -> u8 bucket[B][N] + gmin[B][N/16] + u16 hist slabs
//   k_rowfinal: per-row: slab-sum+scan -> tb -> gmin-gated classify ->
//               f64 group-dots -> fine-bucket select -> label hist -> probs
// No memset, no global atomics, no cooperative launch; poison-safe.

#define NBK 256          // coarse buckets per row histogram (pow2)
#define FNB 1024         // fine buckets for candidate selection (pow2)
#define CAPC 2048        // per-row candidate capacity (expected ~900)
#define BCAP 2048        // per-row below-list capacity (btot < K)
#define MROWS 32         // out-rows per MFMA block (two 16-row tiles)
#define NCHX 64          // code-chunks for MFMA pass
#define NCLS 100

typedef _Float16 half8 __attribute__((ext_vector_type(8)));
typedef float floatx4 __attribute__((ext_vector_type(4)));

static __device__ __forceinline__ unsigned packh2(float a, float b) {
  _Float16 ha = (_Float16)a, hb = (_Float16)b;      // RNE
  unsigned short ua, ub;
  __builtin_memcpy(&ua, &ha, 2); __builtin_memcpy(&ub, &hb, 2);
  return (unsigned)ua | ((unsigned)ub << 16);
}

// shared range math (1-ulp discrepancies absorbed by margins; M>=0.05)
static __device__ __forceinline__ void rowRange(double b1sq, double cmax,
                                                double& lo, double& inv, double& bw) {
  double hr = 0.5 * sqrt(b1sq * cmax) * 1.000001 + 9.0;  // +9 >> M
  lo = 50.0 - hr;
  bw = (2.0 * hr) / (double)NBK;
  inv = (double)NBK / (2.0 * hr);
}

// ---- MFMA A-fragment loader (mfma_f32_16x16x32_f16 layout, m89-verified):
//   A: lane holds A[m = lane&15][k = (lane>>4)*8 + j]; D: reg r = D[(lane>>4)*4+r][lane&15]
static __device__ __forceinline__ void loadA(const unsigned short* __restrict__ out16,
                                             int m0, int mr, int quad,
                                             half8& a00, half8& a01, half8& a10, half8& a11) {
  const uint4* o4 = (const uint4*)out16;
  uint4 u;
  u = o4[(size_t)(m0 + mr) * 8 + quad];          __builtin_memcpy(&a00, &u, 16);
  u = o4[(size_t)(m0 + mr) * 8 + 4 + quad];      __builtin_memcpy(&a01, &u, 16);
  u = o4[(size_t)(m0 + 16 + mr) * 8 + quad];     __builtin_memcpy(&a10, &u, 16);
  u = o4[(size_t)(m0 + 16 + mr) * 8 + 4 + quad]; __builtin_memcpy(&a11, &u, 16);
}

// ============ k_prep: 1024 thr; cvt 4-deep MLP; matmul 16 w-groups ============
__global__ __launch_bounds__(1024) void k_prep(const float* __restrict__ x,
                                               const float* __restrict__ W,
                                               const float* __restrict__ codes,
                                               const int* __restrict__ labels,
                                               int N, int Npad, int D, int B, int nCvt,
                                               unsigned short* __restrict__ codes16,
                                               float* __restrict__ cmaxSlab,
                                               double* __restrict__ out64,
                                               unsigned short* __restrict__ out16,
                                               double* __restrict__ B1sq,
                                               int* __restrict__ shiftp) {
  __shared__ double red[1024];   // 8 KB (matmul reduce)
  __shared__ float xs[2048];     // 8 KB (staged x row)
  __shared__ float fredw[16];
  __shared__ int flag;
  int blk = (int)blockIdx.x, tid = (int)threadIdx.x;
  int lane = tid & 63, wid = tid >> 6;
  if (blk < nCvt) {
    // 256 rows per block, 16 lanes/row, 4 passes; all 4 loads hoisted.
    int gl = tid & 15, g = tid >> 4;                // g in 0..63
    int base = blk * 256;
    int r0 = base + g, r1 = base + 64 + g, r2 = base + 128 + g, r3 = base + 192 + g;
    float4 q0 = {0.f,0.f,0.f,0.f}, q1 = q0, q2 = q0, q3 = q0;
    if (r0 < N) q0 = ((const float4*)(codes + (size_t)r0 * 64))[gl];
    if (r1 < N) q1 = ((const float4*)(codes + (size_t)r1 * 64))[gl];
    if (r2 < N) q2 = ((const float4*)(codes + (size_t)r2 * 64))[gl];
    if (r3 < N) q3 = ((const float4*)(codes + (size_t)r3 * 64))[gl];
    // rows r0..r3 < Npad always (blk < Npad/256): stores unconditional
    uint2 o0, o1, o2, o3;
    o0.x = packh2(q0.x, q0.y); o0.y = packh2(q0.z, q0.w);
    o1.x = packh2(q1.x, q1.y); o1.y = packh2(q1.z, q1.w);
    o2.x = packh2(q2.x, q2.y); o2.y = packh2(q2.z, q2.w);
    o3.x = packh2(q3.x, q3.y); o3.y = packh2(q3.z, q3.w);
    ((uint2*)(codes16 + (size_t)r0 * 64))[gl] = o0;
    ((uint2*)(codes16 + (size_t)r1 * 64))[gl] = o1;
    ((uint2*)(codes16 + (size_t)r2 * 64))[gl] = o2;
    ((uint2*)(codes16 + (size_t)r3 * 64))[gl] = o3;
    float bmax = 0.0f;
#define NRM(qv)                                                            \
    { double c2 = fma((double)(qv).x, (double)(qv).x, 0.0);                \
      c2 = fma((double)(qv).y, (double)(qv).y, c2);                        \
      c2 = fma((double)(qv).z, (double)(qv).z, c2);                        \
      c2 = fma((double)(qv).w, (double)(qv).w, c2);                        \
      c2 += __shfl_xor(c2, 1, 16); c2 += __shfl_xor(c2, 2, 16);            \
      c2 += __shfl_xor(c2, 4, 16); c2 += __shfl_xor(c2, 8, 16);            \
      bmax = fmaxf(bmax, (float)(c2 * 1.000001)); }
    NRM(q0) NRM(q1) NRM(q2) NRM(q3)
#undef NRM
#pragma unroll
    for (int off = 32; off > 0; off >>= 1) bmax = fmaxf(bmax, __shfl_xor(bmax, off, 64));
    if (lane == 0) fredw[wid] = bmax;
    __syncthreads();
    if (tid == 0) {
      float m = fredw[0];
#pragma unroll
      for (int j = 1; j < 16; ++j) m = fmaxf(m, fredw[j]);
      cmaxSlab[blk] = m;                            // plain store (no init needed)
    }
  } else if (blk < nCvt + B) {   // out = x @ W in f64 (+f16 copy), ||out_b||^2
    int b = blk - nCvt;
    const float* xr = x + (size_t)b * D;
    for (int i = tid; i < (D >> 1); i += 1024)
      ((float2*)xs)[i] = ((const float2*)xr)[i];
    __syncthreads();
    int t = tid & 63, w = tid >> 6;    // w in 0..15
    int kc = D >> 4;                   // 128 for D=2048
    int k0 = w * kc;
    double a[8];
#pragma unroll
    for (int j = 0; j < 8; ++j) a[j] = 0.0;
#pragma unroll 2
    for (int k = k0; k < k0 + kc; k += 8) {
#pragma unroll
      for (int j = 0; j < 8; ++j)
        a[j] = fma((double)xs[k + j], (double)W[(size_t)(k + j) * 64 + t], a[j]);
    }
    red[tid] = ((a[0] + a[1]) + (a[2] + a[3])) + ((a[4] + a[5]) + (a[6] + a[7]));
    __syncthreads();
    if (w == 0) {                      // threads 0..63 = wave 0
      double o = 0.0;
#pragma unroll
      for (int j = 0; j < 16; ++j) o += red[t + 64 * j];
      out64[(size_t)b * 64 + t] = o;
      _Float16 h = (_Float16)(float)o;       // RNE
      unsigned short us; __builtin_memcpy(&us, &h, 2);
      out16[(size_t)b * 64 + t] = us;
      double sq = o * o;                     // deterministic butterfly sum
#pragma unroll
      for (int off = 1; off < 64; off <<= 1) sq += __shfl_xor(sq, off, 64);
      if (t == 0) B1sq[b] = sq;
    }
  } else {                       // labels layout: int64 pairs vs int32
    if (tid == 0) flag = 0;
    __syncthreads();
    int m = N < 256 ? N : 256;
    if (tid < m && labels[2 * tid + 1] != 0) atomicOr(&flag, 1);
    __syncthreads();
    if (tid == 0) *shiftp = flag ? 0 : 1;    // label(n)=labels[n<<shift]
  }
}

// ============ k_mhist v5: MROWS=32, 512 thr, + gmin group-min emit ============
__global__ __launch_bounds__(512) void k_mhist(const unsigned short* __restrict__ codes16,
                                               const unsigned short* __restrict__ out16,
                                               const double* __restrict__ B1sq,
                                               const float* __restrict__ cmaxSlab,
                                               int nCvt, int N, int Npad, int cpb, int B,
                                               unsigned short* __restrict__ histg,
                                               unsigned char* __restrict__ buck,
                                               unsigned char* __restrict__ gmin) {
  __shared__ unsigned hist[MROWS * NBK];   // 32 KB
  __shared__ float sP[MROWS], sQ[MROWS], fredw[8];
  int tid = (int)threadIdx.x;
  int lane = tid & 63, wv = tid >> 6;      // wv in 0..7
  int m0 = (int)blockIdx.y * MROWS, cx = (int)blockIdx.x;
  int N16g = (N + 15) >> 4;
  // cmax: wave-reduce + 8-entry combine (exact max, order-independent)
  {
    float m = 0.0f;
    for (int i = tid; i < nCvt; i += 512) m = fmaxf(m, cmaxSlab[i]);
#pragma unroll
    for (int off = 32; off > 0; off >>= 1) m = fmaxf(m, __shfl_xor(m, off, 64));
    if (lane == 0) fredw[wv] = m;
  }
  for (int i = tid; i < MROWS * NBK; i += 512) hist[i] = 0u;
  __syncthreads();
  float cmax;
  { float m = fredw[0];
#pragma unroll
    for (int j = 1; j < 8; ++j) m = fmaxf(m, fredw[j]);
    cmax = m; }
  if (tid < MROWS) {
    double lo, inv, bw;
    rowRange(B1sq[m0 + tid], (double)cmax, lo, inv, bw);
    sP[tid] = (float)(-0.5 * inv);         // bucket = trunc(d*P + Q), monotone in v
    sQ[tid] = (float)((50.0 - lo) * inv);
  }
  __syncthreads();
  int quad = lane >> 4, mr = lane & 15;
  half8 a00, a01, a10, a11;
  loadA(out16, m0, mr, quad, a00, a01, a10, a11);
  float P0[4], Q0[4], P1[4], Q1[4];
#pragma unroll
  for (int r = 0; r < 4; ++r) {
    P0[r] = sP[quad*4 + r];      Q0[r] = sQ[quad*4 + r];
    P1[r] = sP[16 + quad*4 + r]; Q1[r] = sQ[16 + quad*4 + r];
  }
  int cstart = cx * cpb;
  int cend = cstart + cpb; if (cend > N) cend = N;
  const uint4* c4 = (const uint4*)codes16;
  floatx4 z = {0.f, 0.f, 0.f, 0.f};
  for (int base = cstart; base < cend; base += 128) {   // 8 waves x 16 codes
    int nrow = base + wv * 16 + mr;
    int nc = nrow < Npad ? nrow : Npad - 1;
    uint4 ub0 = c4[(size_t)nc * 8 + quad];
    uint4 ub1 = c4[(size_t)nc * 8 + 4 + quad];
    half8 b0, b1;
    __builtin_memcpy(&b0, &ub0, 16); __builtin_memcpy(&b1, &ub1, 16);
    floatx4 d0 = __builtin_amdgcn_mfma_f32_16x16x32_f16(a00, b0, z, 0, 0, 0);
    d0 = __builtin_amdgcn_mfma_f32_16x16x32_f16(a01, b1, d0, 0, 0, 0);
    floatx4 d1 = __builtin_amdgcn_mfma_f32_16x16x32_f16(a10, b0, z, 0, 0, 0);
    d1 = __builtin_amdgcn_mfma_f32_16x16x32_f16(a11, b1, d1, 0, 0, 0);
    int gidx = (base >> 4) + wv;
    bool gok = (gidx < N16g);
#pragma unroll
    for (int r = 0; r < 4; ++r) {
      int bk0 = (int)fmaf(d0[r], P0[r], Q0[r]);
      bk0 = bk0 < 0 ? 0 : (bk0 > NBK-1 ? NBK-1 : bk0);
      int bk1 = (int)fmaf(d1[r], P1[r], Q1[r]);
      bk1 = bk1 < 0 ? 0 : (bk1 > NBK-1 ? NBK-1 : bk1);
      if (nrow < N) {
        atomicAdd(&hist[(quad*4 + r) * NBK + bk0], 1u);   // LDS: local, fast
        buck[(size_t)(m0 + quad*4 + r) * N + nrow] = (unsigned char)bk0;
        atomicAdd(&hist[(16 + quad*4 + r) * NBK + bk1], 1u);
        buck[(size_t)(m0 + 16 + quad*4 + r) * N + nrow] = (unsigned char)bk1;
      }
      // group-min over the 16 mr-lanes of this quad (exec-full here)
      int v0 = nrow < N ? bk0 : 255;
      int v1 = nrow < N ? bk1 : 255;
      int t0;
      t0 = __shfl_xor(v0, 1, 16); v0 = v0 < t0 ? v0 : t0;
      t0 = __shfl_xor(v0, 2, 16); v0 = v0 < t0 ? v0 : t0;
      t0 = __shfl_xor(v0, 4, 16); v0 = v0 < t0 ? v0 : t0;
      t0 = __shfl_xor(v0, 8, 16); v0 = v0 < t0 ? v0 : t0;
      t0 = __shfl_xor(v1, 1, 16); v1 = v1 < t0 ? v1 : t0;
      t0 = __shfl_xor(v1, 2, 16); v1 = v1 < t0 ? v1 : t0;
      t0 = __shfl_xor(v1, 4, 16); v1 = v1 < t0 ? v1 : t0;
      t0 = __shfl_xor(v1, 8, 16); v1 = v1 < t0 ? v1 : t0;
      if (mr == 0 && gok) {
        gmin[(size_t)(m0 + quad*4 + r) * N16g + gidx] = (unsigned char)v0;
        gmin[(size_t)(m0 + 16 + quad*4 + r) * N16g + gidx] = (unsigned char)v1;
      }
    }
  }
  __syncthreads();
  // exclusive slab, plain coalesced u16 stores (counts <= cpb=1664 < 65535)
  for (int i = tid; i < MROWS * NBK; i += 512)
    histg[((size_t)cx * B + (m0 + (i >> 8))) * NBK + (i & (NBK - 1))] =
        (unsigned short)hist[i];
}

// ============ k_rowfinal v6: gmin-gated classify, 12 barriers ============
__global__ __launch_bounds__(1024) void k_rowfinal(const float* __restrict__ codes,
                                                   const double* __restrict__ out64,
                                                   const double* __restrict__ B1sq,
                                                   const float* __restrict__ cmaxSlab,
                                                   const unsigned short* __restrict__ histg,
                                                   const unsigned char* __restrict__ buck,
                                                   const unsigned char* __restrict__ gmin,
                                                   const int* __restrict__ labels,
                                                   const int* __restrict__ shiftp,
                                                   const int* __restrict__ Kp,
                                                   float* __restrict__ outp,
                                                   int nCvt, int N, int B) {
  __shared__ float fredw[16];
  __shared__ unsigned sp[1024];            // slab partials; reused for fine scan
  __shared__ unsigned s[NBK];              // coarse cumulative hist
  __shared__ unsigned wtot[4];
  __shared__ double key[CAPC];             // 16 KB
  __shared__ int kidx[CAPC];               // 8 KB
  __shared__ int blist[BCAP];              // 8 KB
  __shared__ unsigned fhist[FNB];          // 4 KB
  __shared__ unsigned ftot[16];
  __shared__ unsigned short tlist[CAPC];   // 4 KB
  __shared__ double sod[64];
  __shared__ unsigned lab[NCLS];
  __shared__ unsigned ccnt, bcnt, tcnt, sCntLt;
  __shared__ int sTb, sFtb;
  int b = (int)blockIdx.x, tid = (int)threadIdx.x;
  int lane = tid & 63, wid = tid >> 6;

  // ---- init + cmax wave-reduce (order-independent exact max) ----
  {
    float m = (tid < nCvt) ? cmaxSlab[tid] : 0.0f;
    for (int i = tid + 1024; i < nCvt; i += 1024) m = fmaxf(m, cmaxSlab[i]);
#pragma unroll
    for (int off = 32; off > 0; off >>= 1) m = fmaxf(m, __shfl_xor(m, off, 64));
    if (lane == 0) fredw[wid] = m;
  }
  fhist[tid] = 0u;
  if (tid < 64) sod[tid] = out64[(size_t)b * 64 + tid];
  if (tid < NCLS) lab[tid] = 0u;
  if (tid == 0) { ccnt = 0u; bcnt = 0u; tcnt = 0u; sCntLt = 0u; sFtb = FNB; }
  __syncthreads();                                         // 1
  float cmax;
  { float m = fredw[0];
#pragma unroll
    for (int j = 1; j < 16; ++j) m = fmaxf(m, fredw[j]);
    cmax = m; }

  // ---- coarse slab sum (4-way split, 16 coalesced u16 loads/thread) ----
  {
    int bk = tid & 255, cq = tid >> 8;
    unsigned part = 0;
#pragma unroll
    for (int t2 = 0; t2 < 16; ++t2)
      part += (unsigned)histg[((size_t)(cq * 16 + t2) * B + b) * NBK + bk];
    sp[tid] = part;
  }
  __syncthreads();                                         // 2
  {
    unsigned v = 0;
    if (tid < 256) {
      v = sp[tid] + sp[tid + 256] + sp[tid + 512] + sp[tid + 768];
#pragma unroll
      for (int off = 1; off < 64; off <<= 1) {             // wave inclusive scan
        unsigned t = (unsigned)__shfl_up((int)v, off, 64);
        if (lane >= off) v += t;
      }
      if (lane == 63) wtot[wid] = v;
    }
    __syncthreads();                                       // 3
    if (tid < 256) {
      for (int j = 0; j < wid; ++j) v += wtot[j];
      s[tid] = v;                                          // inclusive cumulative
    }
  }
  __syncthreads();                                         // 4
  unsigned K = (unsigned)Kp[0];
  if (tid < 256) {
    unsigned prev = tid ? s[tid - 1] : 0u;
    if (s[tid] >= K && prev < K) sTb = tid;                // exactly one thread
  }
  __syncthreads();                                         // 5
  int tb = sTb;
  double lo, inv, bwd;
  rowRange(B1sq[b], (double)cmax, lo, inv, bwd);
  double S = sqrt(B1sq[b] * (double)cmax);
  double Mtot = 2.0 * (0.5 * S * 1.1e-3 + 0.05) + 1e-3;    // 2M + abs slack
  int q = (int)ceil(Mtot / bwd);
  int belowMax = tb - 1 - q;                               // certainly in top-K
  int candMax = tb + 1 + q;                                // candidate window
  if (candMax > NBK - 1) candMax = NBK - 1;
  unsigned btot = (belowMax >= 0) ? s[belowMax] : 0u;
  int shift = *shiftp;

  // ---- classify: gmin-gated (only flagged 16-code groups touch buck) ----
  {
    int N16g = (N + 15) >> 4;
    const unsigned char* gmr = gmin + (size_t)b * N16g;
    const unsigned char* br  = buck + (size_t)b * N;
    bool fast = (candMax <= 127);                 // hasless valid for c1<=128
    unsigned c1x = (unsigned)(candMax + 1) * 0x01010101u;
#define CLS1(nn, bkv)                                                  \
    { int bk_ = (int)(bkv);                                            \
      if (bk_ <= belowMax) {                                           \
        unsigned p_ = atomicAdd(&bcnt, 1u);                            \
        if (p_ < BCAP) blist[p_] = (nn);                               \
      } else if (bk_ <= candMax) {                                     \
        unsigned p_ = atomicAdd(&ccnt, 1u);                            \
        if (p_ < CAPC) kidx[p_] = (nn);                                \
      } }
#define DOGRP(g_)                                                      \
    { int n0_ = (g_) << 4;                                             \
      if (n0_ + 15 < N) {                                              \
        uint4 v_ = *(const uint4*)(br + n0_);                          \
        unsigned u_;                                                   \
        u_ = v_.x; CLS1(n0_+0,  u_ & 0xFF) CLS1(n0_+1,  (u_>>8)&0xFF)  \
                   CLS1(n0_+2,  (u_>>16)&0xFF) CLS1(n0_+3,  u_>>24)    \
        u_ = v_.y; CLS1(n0_+4,  u_ & 0xFF) CLS1(n0_+5,  (u_>>8)&0xFF)  \
                   CLS1(n0_+6,  (u_>>16)&0xFF) CLS1(n0_+7,  u_>>24)    \
        u_ = v_.z; CLS1(n0_+8,  u_ & 0xFF) CLS1(n0_+9,  (u_>>8)&0xFF)  \
                   CLS1(n0_+10, (u_>>16)&0xFF) CLS1(n0_+11, u_>>24)    \
        u_ = v_.w; CLS1(n0_+12, u_ & 0xFF) CLS1(n0_+13, (u_>>8)&0xFF)  \
                   CLS1(n0_+14, (u_>>16)&0xFF) CLS1(n0_+15, u_>>24)    \
      } else {                                                         \
        for (int k_ = n0_; k_ < N; ++k_) CLS1(k_, br[k_])              \
      } }
    int nw4 = N16g >> 2;
    for (int i = tid; i < nw4; i += 1024) {
      unsigned w = *(const unsigned*)(gmr + 4 * i);
      bool any = fast ? (((w - c1x) & ~w & 0x80808080u) != 0) : true;
      if (any) {
#pragma unroll
        for (int j = 0; j < 4; ++j) {
          int gb = (int)((w >> (8 * j)) & 0xFFu);
          if (gb <= candMax) DOGRP(4 * i + j)
        }
      }
    }
    for (int g = (nw4 << 2) + tid; g < N16g; g += 1024) {  // tail groups
      if ((int)gmr[g] <= candMax) DOGRP(g)
    }
#undef DOGRP
#undef CLS1
  }
  __syncthreads();                                         // 6

  // ---- below labels (exec-full) + candidate exact dots (2-deep) ----
  {
    int bm = (int)bcnt; if (bm > BCAP) bm = BCAP;
    for (int i = tid; i < bm; i += 1024)
      atomicAdd(&lab[labels[(size_t)blist[i] << shift]], 1u);
  }
  int cc = (int)ccnt; if (cc > CAPC) cc = CAPC;
  {
    int g = tid >> 4, gl = tid & 15;                       // 64 groups x 16 lanes
    for (int i = g; i < cc; i += 128) {
      int i1 = i + 64; bool h1 = i1 < cc;
      int n0 = kidx[i];
      int n1 = h1 ? kidx[i1] : n0;
      float4 qv0 = ((const float4*)(codes + (size_t)n0 * 64))[gl];
      float4 qv1 = ((const float4*)(codes + (size_t)n1 * 64))[gl];
      double p0 = fma((double)qv0.x, sod[gl*4+0], 0.0);
      p0 = fma((double)qv0.y, sod[gl*4+1], p0);
      p0 = fma((double)qv0.z, sod[gl*4+2], p0);
      p0 = fma((double)qv0.w, sod[gl*4+3], p0);
      double p1 = fma((double)qv1.x, sod[gl*4+0], 0.0);
      p1 = fma((double)qv1.y, sod[gl*4+1], p1);
      p1 = fma((double)qv1.z, sod[gl*4+2], p1);
      p1 = fma((double)qv1.w, sod[gl*4+3], p1);
      p0 += __shfl_xor(p0, 1, 16); p1 += __shfl_xor(p1, 1, 16);
      p0 += __shfl_xor(p0, 2, 16); p1 += __shfl_xor(p1, 2, 16);
      p0 += __shfl_xor(p0, 4, 16); p1 += __shfl_xor(p1, 4, 16);
      p0 += __shfl_xor(p0, 8, 16); p1 += __shfl_xor(p1, 8, 16);
      if (gl == 0) {
        key[i] = fma(p0, -0.5, 50.0);
        if (h1) key[i1] = fma(p1, -0.5, 50.0);
      }
    }
  }
  __syncthreads();                                         // 7

  // ---- fine-bucket selection over exact keys (monotone map) ----
  int need = (int)K - (int)btot;                           // >= 1
  double fLo = lo + (double)(belowMax + 1) * bwd - Mtot;
  double fInv = (double)FNB / ((double)(candMax - belowMax) * bwd + 2.0 * Mtot);
  for (int i = tid; i < cc; i += 1024) {
    int fb = (int)((key[i] - fLo) * fInv);
    fb = fb < 0 ? 0 : (fb > FNB - 1 ? FNB - 1 : fb);
    atomicAdd(&fhist[fb], 1u);
  }
  __syncthreads();                                         // 8
  {
    unsigned v = fhist[tid];
#pragma unroll
    for (int off = 1; off < 64; off <<= 1) {
      unsigned t = (unsigned)__shfl_up((int)v, off, 64);
      if (lane >= off) v += t;
    }
    if (lane == 63) ftot[wid] = v;
    sp[tid] = v;                                           // wave-local inclusive
  }
  __syncthreads();                                         // 9
  {
    unsigned off = 0;
    for (int j = 0; j < wid; ++j) off += ftot[j];
    unsigned ci = sp[tid] + off;                           // inclusive cum
    unsigned ce = ci - fhist[tid];                         // exclusive cum
    if ((int)ci >= need && (int)ce < need) { sFtb = tid; sCntLt = ce; }
  }
  __syncthreads();                                         // 10
  int ftb = sFtb;
  // emit: certain candidates -> labels; threshold fine-bucket -> tlist
  for (int i = tid; i < cc; i += 1024) {
    int fb = (int)((key[i] - fLo) * fInv);
    fb = fb < 0 ? 0 : (fb > FNB - 1 ? FNB - 1 : fb);
    if (fb < ftb) {
      atomicAdd(&lab[labels[(size_t)kidx[i] << shift]], 1u);
    } else if (fb == ftb) {
      unsigned p_ = atomicAdd(&tcnt, 1u);
      if (p_ < CAPC) tlist[p_] = (unsigned short)i;
    }
  }
  __syncthreads();                                         // 11
  {
    int tn = (int)tcnt; if (tn > CAPC) tn = CAPC;
    int rem = need - (int)sCntLt;                          // in [1, fhist[ftb]]
    for (int j = tid; j < tn; j += 1024) {
      int i = (int)tlist[j];
      double ki = key[i]; int ii = kidx[i];
      int rank = 0;
      for (int j2 = 0; j2 < tn; ++j2) {
        int i2 = (int)tlist[j2];
        double k2 = key[i2];
        rank += (k2 < ki || (k2 == ki && kidx[i2] < ii)) ? 1 : 0;
      }
      if (rank < rem) atomicAdd(&lab[labels[(size_t)ii << shift]], 1u);
    }
  }
  __syncthreads();                                         // 12
  double Kd = (double)K;
  for (int c = tid; c < NCLS; c += 1024)
    outp[b * NCLS + c] = (float)((double)lab[c] / Kd);
}

extern "C" void kernel_launch(void* const* d_in, const int* in_sizes, int n_in,
                              void* d_out, int out_size, void* d_ws, size_t ws_size,
                              hipStream_t stream) {
  const float* x     = (const float*)d_in[0];
  const float* W     = (const float*)d_in[1];
  const float* codes = (const float*)d_in[2];
  const int* labels  = (const int*)d_in[3];
  const int* Kp      = (const int*)d_in[4];

  const int B = out_size / NCLS;             // 256
  const int N = in_sizes[3];                 // 100000
  const int D = in_sizes[0] / B;             // 2048
  const int Npad = (N + 255) & ~255;         // 100096
  const int cpb = (((N + NCHX - 1) / NCHX) + 127) & ~127;  // 1664 (mult of 128)
  const int nCvt = Npad / 256;               // 391 cvt blocks (256 rows each)
  const int N16g = (N + 15) >> 4;            // 6250 groups per row

  // ws layout; nothing needs host-side init (all state written before read).
  char* p = (char*)d_ws;
  double* out64      = (double*)p;   p += (size_t)B * 64 * sizeof(double);       // 128 KB
  unsigned short* out16 = (unsigned short*)p; p += (size_t)B * 64 * 2;           // 32 KB
  double* B1sq       = (double*)p;   p += (size_t)B * sizeof(double);            // 2 KB
  int* shiftp        = (int*)p;      p += 64;
  float* cmaxSlab    = (float*)p;    p += 4096;                                  // nCvt floats
  unsigned short* histg = (unsigned short*)p; p += (size_t)NCHX * B * NBK * 2;   // 8 MB
  unsigned char* buck   = (unsigned char*)p;  p += (size_t)B * N;                // 25.6 MB
  unsigned char* gmin   = (unsigned char*)p;  p += ((size_t)B * N16g + 63) & ~63ull; // 1.6 MB
  unsigned short* codes16 = (unsigned short*)p;                                  // 12.8 MB

  k_prep<<<nCvt + B + 1, 1024, 0, stream>>>(x, W, codes, labels, N, Npad, D, B, nCvt,
                                            codes16, cmaxSlab, out64, out16, B1sq, shiftp);
  k_mhist<<<dim3(NCHX, B / MROWS), 512, 0, stream>>>(codes16, out16, B1sq, cmaxSlab,
                                                     nCvt, N, Npad, cpb, B, histg, buck, gmin);
  k_rowfinal<<<B, 1024, 0, stream>>>(codes, out64, B1sq, cmaxSlab, histg, buck, gmin,
                                     labels, shiftp, Kp, (float*)d_out, nCvt, N, B);
}

// Round 12
// 155.688 us; speedup vs baseline: 1.0689x; 1.0689x over previous
//
#include <hip/hip_runtime.h>
#include <hip/hip_fp16.h>

// B=256 queries, D=2048, d=64 hash dim, N=100000 database, C=100 classes,
// K=1000 SMALLEST-sim selection. Inputs f32, labels int, output f32.
//
// R18: revert R17's gmin (regressed +14us: double-indirection classify +
// shfl-min in mhist hot loop). Base = R16 (152.7us, ==R14 within noise).
// One change: k_prep at 512 threads/block — R14-R17 ran 647x1024thr =
// 2.53 scheduling rounds over 256 CUs (straggler tail ~1/3 of prep time);
// now cvt 128 rows/block (782 blocks) + matmul 8 w-groups (256 blocks) =
// 1039x512thr at 4 blocks/CU = 1.01 rounds. Same math, same per-row norms,
// same global cmax (grouping differs, max identical).
//   k_prep    : detect + codes f32->f16 (+max||c||^2 slab) + out=x@W f64/f16
//   k_mhist   : MFMA screen -> u8 bucket[B][N] + u16 hist slabs [NCHX][B][NBK]
//   k_rowfinal: per-row: slab-sum+scan -> tb -> hasless-gated classify ->
//               f64 group-dots -> fine-bucket select -> label hist -> probs
// No memset, no global atomics, no cooperative launch; poison-safe.

#define NBK 256          // coarse buckets per row histogram (pow2)
#define FNB 1024         // fine buckets for candidate selection (pow2)
#define CAPC 2048        // per-row candidate capacity (expected ~900)
#define BCAP 2048        // per-row below-list capacity (btot < K)
#define MROWS 32         // out-rows per MFMA block (two 16-row tiles)
#define NCHX 64          // code-chunks for MFMA pass
#define NCLS 100

typedef _Float16 half8 __attribute__((ext_vector_type(8)));
typedef float floatx4 __attribute__((ext_vector_type(4)));

static __device__ __forceinline__ unsigned packh2(float a, float b) {
  _Float16 ha = (_Float16)a, hb = (_Float16)b;      // RNE
  unsigned short ua, ub;
  __builtin_memcpy(&ua, &ha, 2); __builtin_memcpy(&ub, &hb, 2);
  return (unsigned)ua | ((unsigned)ub << 16);
}

// shared range math (1-ulp discrepancies absorbed by margins; M>=0.05)
static __device__ __forceinline__ void rowRange(double b1sq, double cmax,
                                                double& lo, double& inv, double& bw) {
  double hr = 0.5 * sqrt(b1sq * cmax) * 1.000001 + 9.0;  // +9 >> M
  lo = 50.0 - hr;
  bw = (2.0 * hr) / (double)NBK;
  inv = (double)NBK / (2.0 * hr);
}

// ---- MFMA A-fragment loader (mfma_f32_16x16x32_f16 layout, m89-verified):
//   A: lane holds A[m = lane&15][k = (lane>>4)*8 + j]; D: reg r = D[(lane>>4)*4+r][lane&15]
static __device__ __forceinline__ void loadA(const unsigned short* __restrict__ out16,
                                             int m0, int mr, int quad,
                                             half8& a00, half8& a01, half8& a10, half8& a11) {
  const uint4* o4 = (const uint4*)out16;
  uint4 u;
  u = o4[(size_t)(m0 + mr) * 8 + quad];          __builtin_memcpy(&a00, &u, 16);
  u = o4[(size_t)(m0 + mr) * 8 + 4 + quad];      __builtin_memcpy(&a01, &u, 16);
  u = o4[(size_t)(m0 + 16 + mr) * 8 + quad];     __builtin_memcpy(&a10, &u, 16);
  u = o4[(size_t)(m0 + 16 + mr) * 8 + 4 + quad]; __builtin_memcpy(&a11, &u, 16);
}

// ============ k_prep v4: 512 thr/block — 1039 blocks, 4/CU, ~1 round ============
__global__ __launch_bounds__(512) void k_prep(const float* __restrict__ x,
                                              const float* __restrict__ W,
                                              const float* __restrict__ codes,
                                              const int* __restrict__ labels,
                                              int N, int Npad, int D, int B, int nCvt,
                                              unsigned short* __restrict__ codes16,
                                              float* __restrict__ cmaxSlab,
                                              double* __restrict__ out64,
                                              unsigned short* __restrict__ out16,
                                              double* __restrict__ B1sq,
                                              int* __restrict__ shiftp) {
  __shared__ double red[512];    // 4 KB (matmul reduce)
  __shared__ float xs[2048];     // 8 KB (staged x row)
  __shared__ float fredw[8];
  __shared__ int flag;
  int blk = (int)blockIdx.x, tid = (int)threadIdx.x;
  int lane = tid & 63, wid = tid >> 6;     // wid in 0..7
  if (blk < nCvt) {
    // 128 rows per block, 16 lanes/row, 4 passes; all 4 loads hoisted.
    int gl = tid & 15, g = tid >> 4;                // g in 0..31
    int base = blk * 128;
    int r0 = base + g, r1 = base + 32 + g, r2 = base + 64 + g, r3 = base + 96 + g;
    float4 q0 = {0.f,0.f,0.f,0.f}, q1 = q0, q2 = q0, q3 = q0;
    if (r0 < N) q0 = ((const float4*)(codes + (size_t)r0 * 64))[gl];
    if (r1 < N) q1 = ((const float4*)(codes + (size_t)r1 * 64))[gl];
    if (r2 < N) q2 = ((const float4*)(codes + (size_t)r2 * 64))[gl];
    if (r3 < N) q3 = ((const float4*)(codes + (size_t)r3 * 64))[gl];
    // rows r0..r3 < Npad always (blk < Npad/128): stores unconditional
    uint2 o0, o1, o2, o3;
    o0.x = packh2(q0.x, q0.y); o0.y = packh2(q0.z, q0.w);
    o1.x = packh2(q1.x, q1.y); o1.y = packh2(q1.z, q1.w);
    o2.x = packh2(q2.x, q2.y); o2.y = packh2(q2.z, q2.w);
    o3.x = packh2(q3.x, q3.y); o3.y = packh2(q3.z, q3.w);
    ((uint2*)(codes16 + (size_t)r0 * 64))[gl] = o0;
    ((uint2*)(codes16 + (size_t)r1 * 64))[gl] = o1;
    ((uint2*)(codes16 + (size_t)r2 * 64))[gl] = o2;
    ((uint2*)(codes16 + (size_t)r3 * 64))[gl] = o3;
    float bmax = 0.0f;
#define NRM(qv)                                                            \
    { double c2 = fma((double)(qv).x, (double)(qv).x, 0.0);                \
      c2 = fma((double)(qv).y, (double)(qv).y, c2);                        \
      c2 = fma((double)(qv).z, (double)(qv).z, c2);                        \
      c2 = fma((double)(qv).w, (double)(qv).w, c2);                        \
      c2 += __shfl_xor(c2, 1, 16); c2 += __shfl_xor(c2, 2, 16);            \
      c2 += __shfl_xor(c2, 4, 16); c2 += __shfl_xor(c2, 8, 16);            \
      bmax = fmaxf(bmax, (float)(c2 * 1.000001)); }
    NRM(q0) NRM(q1) NRM(q2) NRM(q3)
#undef NRM
#pragma unroll
    for (int off = 32; off > 0; off >>= 1) bmax = fmaxf(bmax, __shfl_xor(bmax, off, 64));
    if (lane == 0) fredw[wid] = bmax;
    __syncthreads();
    if (tid == 0) {
      float m = fredw[0];
#pragma unroll
      for (int j = 1; j < 8; ++j) m = fmaxf(m, fredw[j]);
      cmaxSlab[blk] = m;                            // plain store (no init needed)
    }
  } else if (blk < nCvt + B) {   // out = x @ W in f64 (+f16 copy), ||out_b||^2
    int b = blk - nCvt;
    const float* xr = x + (size_t)b * D;
    for (int i = tid; i < (D >> 1); i += 512)
      ((float2*)xs)[i] = ((const float2*)xr)[i];
    __syncthreads();
    int t = tid & 63, w = tid >> 6;    // w in 0..7
    int kc = D >> 3;                   // 256 for D=2048
    int k0 = w * kc;
    double a[8];
#pragma unroll
    for (int j = 0; j < 8; ++j) a[j] = 0.0;
#pragma unroll 2
    for (int k = k0; k < k0 + kc; k += 8) {
#pragma unroll
      for (int j = 0; j < 8; ++j)
        a[j] = fma((double)xs[k + j], (double)W[(size_t)(k + j) * 64 + t], a[j]);
    }
    red[tid] = ((a[0] + a[1]) + (a[2] + a[3])) + ((a[4] + a[5]) + (a[6] + a[7]));
    __syncthreads();
    if (w == 0) {                      // threads 0..63 = wave 0
      double o = 0.0;
#pragma unroll
      for (int j = 0; j < 8; ++j) o += red[t + 64 * j];
      out64[(size_t)b * 64 + t] = o;
      _Float16 h = (_Float16)(float)o;       // RNE
      unsigned short us; __builtin_memcpy(&us, &h, 2);
      out16[(size_t)b * 64 + t] = us;
      double sq = o * o;                     // deterministic butterfly sum
#pragma unroll
      for (int off = 1; off < 64; off <<= 1) sq += __shfl_xor(sq, off, 64);
      if (t == 0) B1sq[b] = sq;
    }
  } else {                       // labels layout: int64 pairs vs int32
    if (tid == 0) flag = 0;
    __syncthreads();
    int m = N < 256 ? N : 256;
    if (tid < m && labels[2 * tid + 1] != 0) atomicOr(&flag, 1);
    __syncthreads();
    if (tid == 0) *shiftp = flag ? 0 : 1;    // label(n)=labels[n<<shift]
  }
}

// ============ k_mhist: MROWS=32, 512 thr (16 waves/CU), direct stores ============
__global__ __launch_bounds__(512) void k_mhist(const unsigned short* __restrict__ codes16,
                                               const unsigned short* __restrict__ out16,
                                               const double* __restrict__ B1sq,
                                               const float* __restrict__ cmaxSlab,
                                               int nCvt, int N, int Npad, int cpb, int B,
                                               unsigned short* __restrict__ histg,
                                               unsigned char* __restrict__ buck) {
  __shared__ unsigned hist[MROWS * NBK];   // 32 KB
  __shared__ float sP[MROWS], sQ[MROWS], fredw[8];
  int tid = (int)threadIdx.x;
  int lane = tid & 63, wv = tid >> 6;      // wv in 0..7
  int m0 = (int)blockIdx.y * MROWS, cx = (int)blockIdx.x;
  // cmax: wave-reduce + 8-entry combine (exact max, order-independent)
  {
    float m = 0.0f;
    for (int i = tid; i < nCvt; i += 512) m = fmaxf(m, cmaxSlab[i]);
#pragma unroll
    for (int off = 32; off > 0; off >>= 1) m = fmaxf(m, __shfl_xor(m, off, 64));
    if (lane == 0) fredw[wv] = m;
  }
  for (int i = tid; i < MROWS * NBK; i += 512) hist[i] = 0u;
  __syncthreads();
  float cmax;
  { float m = fredw[0];
#pragma unroll
    for (int j = 1; j < 8; ++j) m = fmaxf(m, fredw[j]);
    cmax = m; }
  if (tid < MROWS) {
    double lo, inv, bw;
    rowRange(B1sq[m0 + tid], (double)cmax, lo, inv, bw);
    sP[tid] = (float)(-0.5 * inv);         // bucket = trunc(d*P + Q), monotone in v
    sQ[tid] = (float)((50.0 - lo) * inv);
  }
  __syncthreads();
  int quad = lane >> 4, mr = lane & 15;
  half8 a00, a01, a10, a11;
  loadA(out16, m0, mr, quad, a00, a01, a10, a11);
  float P0[4], Q0[4], P1[4], Q1[4];
#pragma unroll
  for (int r = 0; r < 4; ++r) {
    P0[r] = sP[quad*4 + r];      Q0[r] = sQ[quad*4 + r];
    P1[r] = sP[16 + quad*4 + r]; Q1[r] = sQ[16 + quad*4 + r];
  }
  int cstart = cx * cpb;
  int cend = cstart + cpb; if (cend > N) cend = N;
  const uint4* c4 = (const uint4*)codes16;
  floatx4 z = {0.f, 0.f, 0.f, 0.f};
  for (int base = cstart; base < cend; base += 128) {   // 8 waves x 16 codes
    int nrow = base + wv * 16 + mr;
    int nc = nrow < Npad ? nrow : Npad - 1;
    uint4 ub0 = c4[(size_t)nc * 8 + quad];
    uint4 ub1 = c4[(size_t)nc * 8 + 4 + quad];
    half8 b0, b1;
    __builtin_memcpy(&b0, &ub0, 16); __builtin_memcpy(&b1, &ub1, 16);
    floatx4 d0 = __builtin_amdgcn_mfma_f32_16x16x32_f16(a00, b0, z, 0, 0, 0);
    d0 = __builtin_amdgcn_mfma_f32_16x16x32_f16(a01, b1, d0, 0, 0, 0);
    floatx4 d1 = __builtin_amdgcn_mfma_f32_16x16x32_f16(a10, b0, z, 0, 0, 0);
    d1 = __builtin_amdgcn_mfma_f32_16x16x32_f16(a11, b1, d1, 0, 0, 0);
    if (nrow < N) {
#pragma unroll
      for (int r = 0; r < 4; ++r) {
        int bk0 = (int)fmaf(d0[r], P0[r], Q0[r]);
        bk0 = bk0 < 0 ? 0 : (bk0 > NBK-1 ? NBK-1 : bk0);
        atomicAdd(&hist[(quad*4 + r) * NBK + bk0], 1u);   // LDS: local, fast
        buck[(size_t)(m0 + quad*4 + r) * N + nrow] = (unsigned char)bk0;
        int bk1 = (int)fmaf(d1[r], P1[r], Q1[r]);
        bk1 = bk1 < 0 ? 0 : (bk1 > NBK-1 ? NBK-1 : bk1);
        atomicAdd(&hist[(16 + quad*4 + r) * NBK + bk1], 1u);
        buck[(size_t)(m0 + 16 + quad*4 + r) * N + nrow] = (unsigned char)bk1;
      }
    }
  }
  __syncthreads();
  // exclusive slab, plain coalesced u16 stores (counts <= cpb=1664 < 65535)
  for (int i = tid; i < MROWS * NBK; i += 512)
    histg[((size_t)cx * B + (m0 + (i >> 8))) * NBK + (i & (NBK - 1))] =
        (unsigned short)hist[i];
}

// ============ k_rowfinal: R12 structure (12 barriers) + hasless word-gate ============
__global__ __launch_bounds__(1024) void k_rowfinal(const float* __restrict__ codes,
                                                   const double* __restrict__ out64,
                                                   const double* __restrict__ B1sq,
                                                   const float* __restrict__ cmaxSlab,
                                                   const unsigned short* __restrict__ histg,
                                                   const unsigned char* __restrict__ buck,
                                                   const int* __restrict__ labels,
                                                   const int* __restrict__ shiftp,
                                                   const int* __restrict__ Kp,
                                                   float* __restrict__ outp,
                                                   int nCvt, int N, int B) {
  __shared__ float fredw[16];
  __shared__ unsigned sp[1024];            // slab partials; reused for fine scan
  __shared__ unsigned s[NBK];              // coarse cumulative hist
  __shared__ unsigned wtot[4];
  __shared__ double key[CAPC];             // 16 KB
  __shared__ int kidx[CAPC];               // 8 KB
  __shared__ int blist[BCAP];              // 8 KB
  __shared__ unsigned fhist[FNB];          // 4 KB
  __shared__ unsigned ftot[16];
  __shared__ unsigned short tlist[CAPC];   // 4 KB
  __shared__ double sod[64];
  __shared__ unsigned lab[NCLS];
  __shared__ unsigned ccnt, bcnt, tcnt, sCntLt;
  __shared__ int sTb, sFtb;
  int b = (int)blockIdx.x, tid = (int)threadIdx.x;
  int lane = tid & 63, wid = tid >> 6;

  // ---- init + cmax wave-reduce (order-independent exact max) ----
  {
    float m = (tid < nCvt) ? cmaxSlab[tid] : 0.0f;
    for (int i = tid + 1024; i < nCvt; i += 1024) m = fmaxf(m, cmaxSlab[i]);
#pragma unroll
    for (int off = 32; off > 0; off >>= 1) m = fmaxf(m, __shfl_xor(m, off, 64));
    if (lane == 0) fredw[wid] = m;
  }
  fhist[tid] = 0u;
  if (tid < 64) sod[tid] = out64[(size_t)b * 64 + tid];
  if (tid < NCLS) lab[tid] = 0u;
  if (tid == 0) { ccnt = 0u; bcnt = 0u; tcnt = 0u; sCntLt = 0u; sFtb = FNB; }
  __syncthreads();                                         // 1
  float cmax;
  { float m = fredw[0];
#pragma unroll
    for (int j = 1; j < 16; ++j) m = fmaxf(m, fredw[j]);
    cmax = m; }

  // ---- coarse slab sum (4-way split, 16 coalesced u16 loads/thread) ----
  {
    int bk = tid & 255, cq = tid >> 8;
    unsigned part = 0;
#pragma unroll
    for (int t2 = 0; t2 < 16; ++t2)
      part += (unsigned)histg[((size_t)(cq * 16 + t2) * B + b) * NBK + bk];
    sp[tid] = part;
  }
  __syncthreads();                                         // 2
  {
    unsigned v = 0;
    if (tid < 256) {
      v = sp[tid] + sp[tid + 256] + sp[tid + 512] + sp[tid + 768];
#pragma unroll
      for (int off = 1; off < 64; off <<= 1) {             // wave inclusive scan
        unsigned t = (unsigned)__shfl_up((int)v, off, 64);
        if (lane >= off) v += t;
      }
      if (lane == 63) wtot[wid] = v;
    }
    __syncthreads();                                       // 3
    if (tid < 256) {
      for (int j = 0; j < wid; ++j) v += wtot[j];
      s[tid] = v;                                          // inclusive cumulative
    }
  }
  __syncthreads();                                         // 4
  unsigned K = (unsigned)Kp[0];
  if (tid < 256) {
    unsigned prev = tid ? s[tid - 1] : 0u;
    if (s[tid] >= K && prev < K) sTb = tid;                // exactly one thread
  }
  __syncthreads();                                         // 5
  int tb = sTb;
  double lo, inv, bwd;
  rowRange(B1sq[b], (double)cmax, lo, inv, bwd);
  double S = sqrt(B1sq[b] * (double)cmax);
  double Mtot = 2.0 * (0.5 * S * 1.1e-3 + 0.05) + 1e-3;    // 2M + abs slack
  int q = (int)ceil(Mtot / bwd);
  int belowMax = tb - 1 - q;                               // certainly in top-K
  int candMax = tb + 1 + q;                                // candidate window
  if (candMax > NBK - 1) candMax = NBK - 1;
  unsigned btot = (belowMax >= 0) ? s[belowMax] : 0u;
  int shift = *shiftp;

  // ---- classify stream: hasless word-gate + block-wide lists, 2-deep MLP ----
  {
    const uint4* bw16 = (const uint4*)(buck + (size_t)b * N);
    int nw16 = N >> 4;
    bool fast = (candMax <= 127);                 // hasless valid for c1<=128
    unsigned c1x = (unsigned)(candMax + 1) * 0x01010101u;
#define CLS1(nn, bkv)                                                  \
    { int bk_ = (int)(bkv);                                            \
      if (bk_ <= belowMax) {                                           \
        unsigned p_ = atomicAdd(&bcnt, 1u);                            \
        if (p_ < BCAP) blist[p_] = (nn);                               \
      } else if (bk_ <= candMax) {                                     \
        unsigned p_ = atomicAdd(&ccnt, 1u);                            \
        if (p_ < CAPC) kidx[p_] = (nn);                                \
      } }
#define PROCW(w_, nb)                                                  \
    if (!fast || (((w_) - c1x) & ~(w_) & 0x80808080u)) {               \
      CLS1((nb)+0, (w_) & 0xFF)         CLS1((nb)+1, ((w_) >> 8) & 0xFF) \
      CLS1((nb)+2, ((w_) >> 16) & 0xFF) CLS1((nb)+3, (w_) >> 24)       \
    }
    for (int i = tid; i < nw16; i += 2048) {
      uint4 v0 = bw16[i];
      int i1 = i + 1024; bool h1 = i1 < nw16;
      uint4 v1 = {0u, 0u, 0u, 0u};
      if (h1) v1 = bw16[i1];
      int nb0 = i << 4;
      PROCW(v0.x, nb0) PROCW(v0.y, nb0 + 4) PROCW(v0.z, nb0 + 8) PROCW(v0.w, nb0 + 12)
      if (h1) {
        int nb1 = i1 << 4;
        PROCW(v1.x, nb1) PROCW(v1.y, nb1 + 4) PROCW(v1.z, nb1 + 8) PROCW(v1.w, nb1 + 12)
      }
    }
#undef PROCW
    for (int n = (nw16 << 4) + tid; n < N; n += 1024) {    // tail
      CLS1(n, buck[(size_t)b * N + n])
    }
#undef CLS1
  }
  __syncthreads();                                         // 6

  // ---- below labels (exec-full) + candidate exact dots (independent) ----
  {
    int bm = (int)bcnt; if (bm > BCAP) bm = BCAP;
    for (int i = tid; i < bm; i += 1024)
      atomicAdd(&lab[labels[(size_t)blist[i] << shift]], 1u);
  }
  int cc = (int)ccnt; if (cc > CAPC) cc = CAPC;
  {
    int g = tid >> 4, gl = tid & 15;                       // 64 groups x 16 lanes
    for (int i = g; i < cc; i += 64) {
      int n = kidx[i];
      float4 qv = ((const float4*)(codes + (size_t)n * 64))[gl];
      double p = fma((double)qv.x, sod[gl*4+0], 0.0);
      p = fma((double)qv.y, sod[gl*4+1], p);
      p = fma((double)qv.z, sod[gl*4+2], p);
      p = fma((double)qv.w, sod[gl*4+3], p);
      p += __shfl_xor(p, 1, 16);                           // deterministic butterfly
      p += __shfl_xor(p, 2, 16);
      p += __shfl_xor(p, 4, 16);
      p += __shfl_xor(p, 8, 16);
      if (gl == 0) key[i] = fma(p, -0.5, 50.0);
    }
  }
  __syncthreads();                                         // 7

  // ---- fine-bucket selection over exact keys (monotone map) ----
  int need = (int)K - (int)btot;                           // >= 1
  double fLo = lo + (double)(belowMax + 1) * bwd - Mtot;
  double fInv = (double)FNB / ((double)(candMax - belowMax) * bwd + 2.0 * Mtot);
  for (int i = tid; i < cc; i += 1024) {
    int fb = (int)((key[i] - fLo) * fInv);
    fb = fb < 0 ? 0 : (fb > FNB - 1 ? FNB - 1 : fb);
    atomicAdd(&fhist[fb], 1u);
  }
  __syncthreads();                                         // 8
  {
    unsigned v = fhist[tid];
#pragma unroll
    for (int off = 1; off < 64; off <<= 1) {
      unsigned t = (unsigned)__shfl_up((int)v, off, 64);
      if (lane >= off) v += t;
    }
    if (lane == 63) ftot[wid] = v;
    sp[tid] = v;                                           // wave-local inclusive
  }
  __syncthreads();                                         // 9
  {
    unsigned off = 0;
    for (int j = 0; j < wid; ++j) off += ftot[j];
    unsigned ci = sp[tid] + off;                           // inclusive cum
    unsigned ce = ci - fhist[tid];                         // exclusive cum
    if ((int)ci >= need && (int)ce < need) { sFtb = tid; sCntLt = ce; }
  }
  __syncthreads();                                         // 10
  int ftb = sFtb;
  // emit: certain candidates -> labels; threshold fine-bucket -> tlist
  for (int i = tid; i < cc; i += 1024) {
    int fb = (int)((key[i] - fLo) * fInv);
    fb = fb < 0 ? 0 : (fb > FNB - 1 ? FNB - 1 : fb);
    if (fb < ftb) {
      atomicAdd(&lab[labels[(size_t)kidx[i] << shift]], 1u);
    } else if (fb == ftb) {
      unsigned p_ = atomicAdd(&tcnt, 1u);
      if (p_ < CAPC) tlist[p_] = (unsigned short)i;
    }
  }
  __syncthreads();                                         // 11
  {
    int tn = (int)tcnt; if (tn > CAPC) tn = CAPC;
    int rem = need - (int)sCntLt;                          // in [1, fhist[ftb]]
    for (int j = tid; j < tn; j += 1024) {
      int i = (int)tlist[j];
      double ki = key[i]; int ii = kidx[i];
      int rank = 0;
      for (int j2 = 0; j2 < tn; ++j2) {
        int i2 = (int)tlist[j2];
        double k2 = key[i2];
        rank += (k2 < ki || (k2 == ki && kidx[i2] < ii)) ? 1 : 0;
      }
      if (rank < rem) atomicAdd(&lab[labels[(size_t)ii << shift]], 1u);
    }
  }
  __syncthreads();                                         // 12
  double Kd = (double)K;
  for (int c = tid; c < NCLS; c += 1024)
    outp[b * NCLS + c] = (float)((double)lab[c] / Kd);
}

extern "C" void kernel_launch(void* const* d_in, const int* in_sizes, int n_in,
                              void* d_out, int out_size, void* d_ws, size_t ws_size,
                              hipStream_t stream) {
  const float* x     = (const float*)d_in[0];
  const float* W     = (const float*)d_in[1];
  const float* codes = (const float*)d_in[2];
  const int* labels  = (const int*)d_in[3];
  const int* Kp      = (const int*)d_in[4];

  const int B = out_size / NCLS;             // 256
  const int N = in_sizes[3];                 // 100000
  const int D = in_sizes[0] / B;             // 2048
  const int Npad = (N + 127) & ~127;         // 100096 (mult of 128 and 256)
  const int cpb = (((N + NCHX - 1) / NCHX) + 127) & ~127;  // 1664 (mult of 128)
  const int nCvt = Npad / 128;               // 782 cvt blocks (128 rows each)

  // ws layout; nothing needs host-side init (all state written before read).
  char* p = (char*)d_ws;
  double* out64      = (double*)p;   p += (size_t)B * 64 * sizeof(double);       // 128 KB
  unsigned short* out16 = (unsigned short*)p; p += (size_t)B * 64 * 2;           // 32 KB
  double* B1sq       = (double*)p;   p += (size_t)B * sizeof(double);            // 2 KB
  int* shiftp        = (int*)p;      p += 64;
  float* cmaxSlab    = (float*)p;    p += 4096;                                  // nCvt floats
  unsigned short* histg = (unsigned short*)p; p += (size_t)NCHX * B * NBK * 2;   // 8 MB
  unsigned char* buck   = (unsigned char*)p;  p += (size_t)B * N;                // 25.6 MB
  unsigned short* codes16 = (unsigned short*)p;                                  // 12.8 MB

  k_prep<<<nCvt + B + 1, 512, 0, stream>>>(x, W, codes, labels, N, Npad, D, B, nCvt,
                                           codes16, cmaxSlab, out64, out16, B1sq, shiftp);
  k_mhist<<<dim3(NCHX, B / MROWS), 512, 0, stream>>>(codes16, out16, B1sq, cmaxSlab,
                                                     nCvt, N, Npad, cpb, B, histg, buck);
  k_rowfinal<<<B, 1024, 0, stream>>>(codes, out64, B1sq, cmaxSlab, histg, buck,
                                     labels, shiftp, Kp, (float*)d_out, nCvt, N, B);
}

// Round 13
// 152.561 us; speedup vs baseline: 1.0908x; 1.0205x over previous
//
#include <hip/hip_runtime.h>
#include <hip/hip_fp16.h>

// B=256 queries, D=2048, d=64 hash dim, N=100000 database, C=100 classes,
// K=1000 SMALLEST-sim selection. Inputs f32, labels int, output f32.
//
// R19: measured-best composite. prep = R14 1024-thr (best total 152.4);
// mhist = 512-thr MROWS=32 (16 waves/CU); rowfinal = R12/R14 UNGATED
// classify — cross-round evidence: rowfinal <=42.8us without the hasless
// gate (R13/R14) vs 46.8-48us with it (R15/R16/R18): sparse firing makes
// the gated loop wave-divergent, costing more than the skipped unpack.
//   k_prep    : detect + codes f32->f16 (+max||c||^2 slab) + out=x@W f64/f16
//   k_mhist   : MFMA screen -> u8 bucket[B][N] + u16 hist slabs [NCHX][B][NBK]
//   k_rowfinal: per-row: slab-sum+scan -> tb -> stream buck -> below/cand ->
//               f64 group-dots -> fine-bucket select -> label hist -> probs
// No memset, no global atomics, no cooperative launch; poison-safe.

#define NBK 256          // coarse buckets per row histogram (pow2)
#define FNB 1024         // fine buckets for candidate selection (pow2)
#define CAPC 2048        // per-row candidate capacity (expected ~900)
#define BCAP 2048        // per-row below-list capacity (btot < K)
#define MROWS 32         // out-rows per MFMA block (two 16-row tiles)
#define NCHX 64          // code-chunks for MFMA pass
#define NCLS 100

typedef _Float16 half8 __attribute__((ext_vector_type(8)));
typedef float floatx4 __attribute__((ext_vector_type(4)));

static __device__ __forceinline__ unsigned packh2(float a, float b) {
  _Float16 ha = (_Float16)a, hb = (_Float16)b;      // RNE
  unsigned short ua, ub;
  __builtin_memcpy(&ua, &ha, 2); __builtin_memcpy(&ub, &hb, 2);
  return (unsigned)ua | ((unsigned)ub << 16);
}

// shared range math (1-ulp discrepancies absorbed by margins; M>=0.05)
static __device__ __forceinline__ void rowRange(double b1sq, double cmax,
                                                double& lo, double& inv, double& bw) {
  double hr = 0.5 * sqrt(b1sq * cmax) * 1.000001 + 9.0;  // +9 >> M
  lo = 50.0 - hr;
  bw = (2.0 * hr) / (double)NBK;
  inv = (double)NBK / (2.0 * hr);
}

// ---- MFMA A-fragment loader (mfma_f32_16x16x32_f16 layout, m89-verified):
//   A: lane holds A[m = lane&15][k = (lane>>4)*8 + j]; D: reg r = D[(lane>>4)*4+r][lane&15]
static __device__ __forceinline__ void loadA(const unsigned short* __restrict__ out16,
                                             int m0, int mr, int quad,
                                             half8& a00, half8& a01, half8& a10, half8& a11) {
  const uint4* o4 = (const uint4*)out16;
  uint4 u;
  u = o4[(size_t)(m0 + mr) * 8 + quad];          __builtin_memcpy(&a00, &u, 16);
  u = o4[(size_t)(m0 + mr) * 8 + 4 + quad];      __builtin_memcpy(&a01, &u, 16);
  u = o4[(size_t)(m0 + 16 + mr) * 8 + quad];     __builtin_memcpy(&a10, &u, 16);
  u = o4[(size_t)(m0 + 16 + mr) * 8 + 4 + quad]; __builtin_memcpy(&a11, &u, 16);
}

// ============ k_prep (R14): 1024 thr; cvt 4-deep MLP; matmul 16 w-groups ============
__global__ __launch_bounds__(1024) void k_prep(const float* __restrict__ x,
                                               const float* __restrict__ W,
                                               const float* __restrict__ codes,
                                               const int* __restrict__ labels,
                                               int N, int Npad, int D, int B, int nCvt,
                                               unsigned short* __restrict__ codes16,
                                               float* __restrict__ cmaxSlab,
                                               double* __restrict__ out64,
                                               unsigned short* __restrict__ out16,
                                               double* __restrict__ B1sq,
                                               int* __restrict__ shiftp) {
  __shared__ double red[1024];   // 8 KB (matmul reduce)
  __shared__ float xs[2048];     // 8 KB (staged x row)
  __shared__ float fredw[16];
  __shared__ int flag;
  int blk = (int)blockIdx.x, tid = (int)threadIdx.x;
  int lane = tid & 63, wid = tid >> 6;
  if (blk < nCvt) {
    // 256 rows per block, 16 lanes/row, 4 passes; all 4 loads hoisted.
    int gl = tid & 15, g = tid >> 4;                // g in 0..63
    int base = blk * 256;
    int r0 = base + g, r1 = base + 64 + g, r2 = base + 128 + g, r3 = base + 192 + g;
    float4 q0 = {0.f,0.f,0.f,0.f}, q1 = q0, q2 = q0, q3 = q0;
    if (r0 < N) q0 = ((const float4*)(codes + (size_t)r0 * 64))[gl];
    if (r1 < N) q1 = ((const float4*)(codes + (size_t)r1 * 64))[gl];
    if (r2 < N) q2 = ((const float4*)(codes + (size_t)r2 * 64))[gl];
    if (r3 < N) q3 = ((const float4*)(codes + (size_t)r3 * 64))[gl];
    // rows r0..r3 < Npad always (blk < Npad/256): stores unconditional
    uint2 o0, o1, o2, o3;
    o0.x = packh2(q0.x, q0.y); o0.y = packh2(q0.z, q0.w);
    o1.x = packh2(q1.x, q1.y); o1.y = packh2(q1.z, q1.w);
    o2.x = packh2(q2.x, q2.y); o2.y = packh2(q2.z, q2.w);
    o3.x = packh2(q3.x, q3.y); o3.y = packh2(q3.z, q3.w);
    ((uint2*)(codes16 + (size_t)r0 * 64))[gl] = o0;
    ((uint2*)(codes16 + (size_t)r1 * 64))[gl] = o1;
    ((uint2*)(codes16 + (size_t)r2 * 64))[gl] = o2;
    ((uint2*)(codes16 + (size_t)r3 * 64))[gl] = o3;
    float bmax = 0.0f;
#define NRM(qv)                                                            \
    { double c2 = fma((double)(qv).x, (double)(qv).x, 0.0);                \
      c2 = fma((double)(qv).y, (double)(qv).y, c2);                        \
      c2 = fma((double)(qv).z, (double)(qv).z, c2);                        \
      c2 = fma((double)(qv).w, (double)(qv).w, c2);                        \
      c2 += __shfl_xor(c2, 1, 16); c2 += __shfl_xor(c2, 2, 16);            \
      c2 += __shfl_xor(c2, 4, 16); c2 += __shfl_xor(c2, 8, 16);            \
      bmax = fmaxf(bmax, (float)(c2 * 1.000001)); }
    NRM(q0) NRM(q1) NRM(q2) NRM(q3)
#undef NRM
#pragma unroll
    for (int off = 32; off > 0; off >>= 1) bmax = fmaxf(bmax, __shfl_xor(bmax, off, 64));
    if (lane == 0) fredw[wid] = bmax;
    __syncthreads();
    if (tid == 0) {
      float m = fredw[0];
#pragma unroll
      for (int j = 1; j < 16; ++j) m = fmaxf(m, fredw[j]);
      cmaxSlab[blk] = m;                            // plain store (no init needed)
    }
  } else if (blk < nCvt + B) {   // out = x @ W in f64 (+f16 copy), ||out_b||^2
    int b = blk - nCvt;
    const float* xr = x + (size_t)b * D;
    for (int i = tid; i < (D >> 1); i += 1024)
      ((float2*)xs)[i] = ((const float2*)xr)[i];
    __syncthreads();
    int t = tid & 63, w = tid >> 6;    // w in 0..15
    int kc = D >> 4;                   // 128 for D=2048
    int k0 = w * kc;
    double a[8];
#pragma unroll
    for (int j = 0; j < 8; ++j) a[j] = 0.0;
#pragma unroll 2
    for (int k = k0; k < k0 + kc; k += 8) {
#pragma unroll
      for (int j = 0; j < 8; ++j)
        a[j] = fma((double)xs[k + j], (double)W[(size_t)(k + j) * 64 + t], a[j]);
    }
    red[tid] = ((a[0] + a[1]) + (a[2] + a[3])) + ((a[4] + a[5]) + (a[6] + a[7]));
    __syncthreads();
    if (w == 0) {                      // threads 0..63 = wave 0
      double o = 0.0;
#pragma unroll
      for (int j = 0; j < 16; ++j) o += red[t + 64 * j];
      out64[(size_t)b * 64 + t] = o;
      _Float16 h = (_Float16)(float)o;       // RNE
      unsigned short us; __builtin_memcpy(&us, &h, 2);
      out16[(size_t)b * 64 + t] = us;
      double sq = o * o;                     // deterministic butterfly sum
#pragma unroll
      for (int off = 1; off < 64; off <<= 1) sq += __shfl_xor(sq, off, 64);
      if (t == 0) B1sq[b] = sq;
    }
  } else {                       // labels layout: int64 pairs vs int32
    if (tid == 0) flag = 0;
    __syncthreads();
    int m = N < 256 ? N : 256;
    if (tid < m && labels[2 * tid + 1] != 0) atomicOr(&flag, 1);
    __syncthreads();
    if (tid == 0) *shiftp = flag ? 0 : 1;    // label(n)=labels[n<<shift]
  }
}

// ============ k_mhist: MROWS=32, 512 thr (16 waves/CU), direct stores ============
__global__ __launch_bounds__(512) void k_mhist(const unsigned short* __restrict__ codes16,
                                               const unsigned short* __restrict__ out16,
                                               const double* __restrict__ B1sq,
                                               const float* __restrict__ cmaxSlab,
                                               int nCvt, int N, int Npad, int cpb, int B,
                                               unsigned short* __restrict__ histg,
                                               unsigned char* __restrict__ buck) {
  __shared__ unsigned hist[MROWS * NBK];   // 32 KB
  __shared__ float sP[MROWS], sQ[MROWS], fredw[8];
  int tid = (int)threadIdx.x;
  int lane = tid & 63, wv = tid >> 6;      // wv in 0..7
  int m0 = (int)blockIdx.y * MROWS, cx = (int)blockIdx.x;
  // cmax: wave-reduce + 8-entry combine (exact max, order-independent)
  {
    float m = 0.0f;
    for (int i = tid; i < nCvt; i += 512) m = fmaxf(m, cmaxSlab[i]);
#pragma unroll
    for (int off = 32; off > 0; off >>= 1) m = fmaxf(m, __shfl_xor(m, off, 64));
    if (lane == 0) fredw[wv] = m;
  }
  for (int i = tid; i < MROWS * NBK; i += 512) hist[i] = 0u;
  __syncthreads();
  float cmax;
  { float m = fredw[0];
#pragma unroll
    for (int j = 1; j < 8; ++j) m = fmaxf(m, fredw[j]);
    cmax = m; }
  if (tid < MROWS) {
    double lo, inv, bw;
    rowRange(B1sq[m0 + tid], (double)cmax, lo, inv, bw);
    sP[tid] = (float)(-0.5 * inv);         // bucket = trunc(d*P + Q), monotone in v
    sQ[tid] = (float)((50.0 - lo) * inv);
  }
  __syncthreads();
  int quad = lane >> 4, mr = lane & 15;
  half8 a00, a01, a10, a11;
  loadA(out16, m0, mr, quad, a00, a01, a10, a11);
  float P0[4], Q0[4], P1[4], Q1[4];
#pragma unroll
  for (int r = 0; r < 4; ++r) {
    P0[r] = sP[quad*4 + r];      Q0[r] = sQ[quad*4 + r];
    P1[r] = sP[16 + quad*4 + r]; Q1[r] = sQ[16 + quad*4 + r];
  }
  int cstart = cx * cpb;
  int cend = cstart + cpb; if (cend > N) cend = N;
  const uint4* c4 = (const uint4*)codes16;
  floatx4 z = {0.f, 0.f, 0.f, 0.f};
  for (int base = cstart; base < cend; base += 128) {   // 8 waves x 16 codes
    int nrow = base + wv * 16 + mr;
    int nc = nrow < Npad ? nrow : Npad - 1;
    uint4 ub0 = c4[(size_t)nc * 8 + quad];
    uint4 ub1 = c4[(size_t)nc * 8 + 4 + quad];
    half8 b0, b1;
    __builtin_memcpy(&b0, &ub0, 16); __builtin_memcpy(&b1, &ub1, 16);
    floatx4 d0 = __builtin_amdgcn_mfma_f32_16x16x32_f16(a00, b0, z, 0, 0, 0);
    d0 = __builtin_amdgcn_mfma_f32_16x16x32_f16(a01, b1, d0, 0, 0, 0);
    floatx4 d1 = __builtin_amdgcn_mfma_f32_16x16x32_f16(a10, b0, z, 0, 0, 0);
    d1 = __builtin_amdgcn_mfma_f32_16x16x32_f16(a11, b1, d1, 0, 0, 0);
    if (nrow < N) {
#pragma unroll
      for (int r = 0; r < 4; ++r) {
        int bk0 = (int)fmaf(d0[r], P0[r], Q0[r]);
        bk0 = bk0 < 0 ? 0 : (bk0 > NBK-1 ? NBK-1 : bk0);
        atomicAdd(&hist[(quad*4 + r) * NBK + bk0], 1u);   // LDS: local, fast
        buck[(size_t)(m0 + quad*4 + r) * N + nrow] = (unsigned char)bk0;
        int bk1 = (int)fmaf(d1[r], P1[r], Q1[r]);
        bk1 = bk1 < 0 ? 0 : (bk1 > NBK-1 ? NBK-1 : bk1);
        atomicAdd(&hist[(16 + quad*4 + r) * NBK + bk1], 1u);
        buck[(size_t)(m0 + 16 + quad*4 + r) * N + nrow] = (unsigned char)bk1;
      }
    }
  }
  __syncthreads();
  // exclusive slab, plain coalesced u16 stores (counts <= cpb=1664 < 65535)
  for (int i = tid; i < MROWS * NBK; i += 512)
    histg[((size_t)cx * B + (m0 + (i >> 8))) * NBK + (i & (NBK - 1))] =
        (unsigned short)hist[i];
}

// ============ k_rowfinal (R12/R14): ungated classify, 12 barriers ============
__global__ __launch_bounds__(1024) void k_rowfinal(const float* __restrict__ codes,
                                                   const double* __restrict__ out64,
                                                   const double* __restrict__ B1sq,
                                                   const float* __restrict__ cmaxSlab,
                                                   const unsigned short* __restrict__ histg,
                                                   const unsigned char* __restrict__ buck,
                                                   const int* __restrict__ labels,
                                                   const int* __restrict__ shiftp,
                                                   const int* __restrict__ Kp,
                                                   float* __restrict__ outp,
                                                   int nCvt, int N, int B) {
  __shared__ float fredw[16];
  __shared__ unsigned sp[1024];            // slab partials; reused for fine scan
  __shared__ unsigned s[NBK];              // coarse cumulative hist
  __shared__ unsigned wtot[4];
  __shared__ double key[CAPC];             // 16 KB
  __shared__ int kidx[CAPC];               // 8 KB
  __shared__ int blist[BCAP];              // 8 KB
  __shared__ unsigned fhist[FNB];          // 4 KB
  __shared__ unsigned ftot[16];
  __shared__ unsigned short tlist[CAPC];   // 4 KB
  __shared__ double sod[64];
  __shared__ unsigned lab[NCLS];
  __shared__ unsigned ccnt, bcnt, tcnt, sCntLt;
  __shared__ int sTb, sFtb;
  int b = (int)blockIdx.x, tid = (int)threadIdx.x;
  int lane = tid & 63, wid = tid >> 6;

  // ---- init + cmax wave-reduce (order-independent exact max) ----
  {
    float m = (tid < nCvt) ? cmaxSlab[tid] : 0.0f;
    for (int i = tid + 1024; i < nCvt; i += 1024) m = fmaxf(m, cmaxSlab[i]);
#pragma unroll
    for (int off = 32; off > 0; off >>= 1) m = fmaxf(m, __shfl_xor(m, off, 64));
    if (lane == 0) fredw[wid] = m;
  }
  fhist[tid] = 0u;
  if (tid < 64) sod[tid] = out64[(size_t)b * 64 + tid];
  if (tid < NCLS) lab[tid] = 0u;
  if (tid == 0) { ccnt = 0u; bcnt = 0u; tcnt = 0u; sCntLt = 0u; sFtb = FNB; }
  __syncthreads();                                         // 1
  float cmax;
  { float m = fredw[0];
#pragma unroll
    for (int j = 1; j < 16; ++j) m = fmaxf(m, fredw[j]);
    cmax = m; }

  // ---- coarse slab sum (4-way split, 16 coalesced u16 loads/thread) ----
  {
    int bk = tid & 255, cq = tid >> 8;
    unsigned part = 0;
#pragma unroll
    for (int t2 = 0; t2 < 16; ++t2)
      part += (unsigned)histg[((size_t)(cq * 16 + t2) * B + b) * NBK + bk];
    sp[tid] = part;
  }
  __syncthreads();                                         // 2
  {
    unsigned v = 0;
    if (tid < 256) {
      v = sp[tid] + sp[tid + 256] + sp[tid + 512] + sp[tid + 768];
#pragma unroll
      for (int off = 1; off < 64; off <<= 1) {             // wave inclusive scan
        unsigned t = (unsigned)__shfl_up((int)v, off, 64);
        if (lane >= off) v += t;
      }
      if (lane == 63) wtot[wid] = v;
    }
    __syncthreads();                                       // 3
    if (tid < 256) {
      for (int j = 0; j < wid; ++j) v += wtot[j];
      s[tid] = v;                                          // inclusive cumulative
    }
  }
  __syncthreads();                                         // 4
  unsigned K = (unsigned)Kp[0];
  if (tid < 256) {
    unsigned prev = tid ? s[tid - 1] : 0u;
    if (s[tid] >= K && prev < K) sTb = tid;                // exactly one thread
  }
  __syncthreads();                                         // 5
  int tb = sTb;
  double lo, inv, bwd;
  rowRange(B1sq[b], (double)cmax, lo, inv, bwd);
  double S = sqrt(B1sq[b] * (double)cmax);
  double Mtot = 2.0 * (0.5 * S * 1.1e-3 + 0.05) + 1e-3;    // 2M + abs slack
  int q = (int)ceil(Mtot / bwd);
  int belowMax = tb - 1 - q;                               // certainly in top-K
  int candMax = tb + 1 + q;                                // candidate window
  if (candMax > NBK - 1) candMax = NBK - 1;
  unsigned btot = (belowMax >= 0) ? s[belowMax] : 0u;
  int shift = *shiftp;

  // ---- classify stream: 2-deep MLP grid-stride uint4, ungated unpack ----
  {
    const uint4* bw16 = (const uint4*)(buck + (size_t)b * N);
    int nw16 = N >> 4;
#define CLS1(nn, bkv)                                                  \
    { int bk_ = (int)(bkv);                                            \
      if (bk_ <= belowMax) {                                           \
        unsigned p_ = atomicAdd(&bcnt, 1u);                            \
        if (p_ < BCAP) blist[p_] = (nn);                               \
      } else if (bk_ <= candMax) {                                     \
        unsigned p_ = atomicAdd(&ccnt, 1u);                            \
        if (p_ < CAPC) kidx[p_] = (nn);                                \
      } }
#define PROCV(vv, nb)                                                  \
    { unsigned w_;                                                     \
      w_ = (vv).x; CLS1((nb)+0,  w_ & 0xFF) CLS1((nb)+1,  (w_>>8)&0xFF)\
                   CLS1((nb)+2,  (w_>>16)&0xFF) CLS1((nb)+3,  w_>>24)  \
      w_ = (vv).y; CLS1((nb)+4,  w_ & 0xFF) CLS1((nb)+5,  (w_>>8)&0xFF)\
                   CLS1((nb)+6,  (w_>>16)&0xFF) CLS1((nb)+7,  w_>>24)  \
      w_ = (vv).z; CLS1((nb)+8,  w_ & 0xFF) CLS1((nb)+9,  (w_>>8)&0xFF)\
                   CLS1((nb)+10, (w_>>16)&0xFF) CLS1((nb)+11, w_>>24)  \
      w_ = (vv).w; CLS1((nb)+12, w_ & 0xFF) CLS1((nb)+13, (w_>>8)&0xFF)\
                   CLS1((nb)+14, (w_>>16)&0xFF) CLS1((nb)+15, w_>>24) }
    for (int i = tid; i < nw16; i += 2048) {
      uint4 v0 = bw16[i];
      int i1 = i + 1024; bool h1 = i1 < nw16;
      uint4 v1 = {0u, 0u, 0u, 0u};
      if (h1) v1 = bw16[i1];
      PROCV(v0, i << 4)
      if (h1) PROCV(v1, i1 << 4)
    }
#undef PROCV
    for (int n = (nw16 << 4) + tid; n < N; n += 1024) {    // tail
      CLS1(n, buck[(size_t)b * N + n])
    }
#undef CLS1
  }
  __syncthreads();                                         // 6

  // ---- below labels (exec-full) + candidate exact dots (independent) ----
  {
    int bm = (int)bcnt; if (bm > BCAP) bm = BCAP;
    for (int i = tid; i < bm; i += 1024)
      atomicAdd(&lab[labels[(size_t)blist[i] << shift]], 1u);
  }
  int cc = (int)ccnt; if (cc > CAPC) cc = CAPC;
  {
    int g = tid >> 4, gl = tid & 15;                       // 64 groups x 16 lanes
    for (int i = g; i < cc; i += 64) {
      int n = kidx[i];
      float4 qv = ((const float4*)(codes + (size_t)n * 64))[gl];
      double p = fma((double)qv.x, sod[gl*4+0], 0.0);
      p = fma((double)qv.y, sod[gl*4+1], p);
      p = fma((double)qv.z, sod[gl*4+2], p);
      p = fma((double)qv.w, sod[gl*4+3], p);
      p += __shfl_xor(p, 1, 16);                           // deterministic butterfly
      p += __shfl_xor(p, 2, 16);
      p += __shfl_xor(p, 4, 16);
      p += __shfl_xor(p, 8, 16);
      if (gl == 0) key[i] = fma(p, -0.5, 50.0);
    }
  }
  __syncthreads();                                         // 7

  // ---- fine-bucket selection over exact keys (monotone map) ----
  int need = (int)K - (int)btot;                           // >= 1
  double fLo = lo + (double)(belowMax + 1) * bwd - Mtot;
  double fInv = (double)FNB / ((double)(candMax - belowMax) * bwd + 2.0 * Mtot);
  for (int i = tid; i < cc; i += 1024) {
    int fb = (int)((key[i] - fLo) * fInv);
    fb = fb < 0 ? 0 : (fb > FNB - 1 ? FNB - 1 : fb);
    atomicAdd(&fhist[fb], 1u);
  }
  __syncthreads();                                         // 8
  {
    unsigned v = fhist[tid];
#pragma unroll
    for (int off = 1; off < 64; off <<= 1) {
      unsigned t = (unsigned)__shfl_up((int)v, off, 64);
      if (lane >= off) v += t;
    }
    if (lane == 63) ftot[wid] = v;
    sp[tid] = v;                                           // wave-local inclusive
  }
  __syncthreads();                                         // 9
  {
    unsigned off = 0;
    for (int j = 0; j < wid; ++j) off += ftot[j];
    unsigned ci = sp[tid] + off;                           // inclusive cum
    unsigned ce = ci - fhist[tid];                         // exclusive cum
    if ((int)ci >= need && (int)ce < need) { sFtb = tid; sCntLt = ce; }
  }
  __syncthreads();                                         // 10
  int ftb = sFtb;
  // emit: certain candidates -> labels; threshold fine-bucket -> tlist
  for (int i = tid; i < cc; i += 1024) {
    int fb = (int)((key[i] - fLo) * fInv);
    fb = fb < 0 ? 0 : (fb > FNB - 1 ? FNB - 1 : fb);
    if (fb < ftb) {
      atomicAdd(&lab[labels[(size_t)kidx[i] << shift]], 1u);
    } else if (fb == ftb) {
      unsigned p_ = atomicAdd(&tcnt, 1u);
      if (p_ < CAPC) tlist[p_] = (unsigned short)i;
    }
  }
  __syncthreads();                                         // 11
  {
    int tn = (int)tcnt; if (tn > CAPC) tn = CAPC;
    int rem = need - (int)sCntLt;                          // in [1, fhist[ftb]]
    for (int j = tid; j < tn; j += 1024) {
      int i = (int)tlist[j];
      double ki = key[i]; int ii = kidx[i];
      int rank = 0;
      for (int j2 = 0; j2 < tn; ++j2) {
        int i2 = (int)tlist[j2];
        double k2 = key[i2];
        rank += (k2 < ki || (k2 == ki && kidx[i2] < ii)) ? 1 : 0;
      }
      if (rank < rem) atomicAdd(&lab[labels[(size_t)ii << shift]], 1u);
    }
  }
  __syncthreads();                                         // 12
  double Kd = (double)K;
  for (int c = tid; c < NCLS; c += 1024)
    outp[b * NCLS + c] = (float)((double)lab[c] / Kd);
}

extern "C" void kernel_launch(void* const* d_in, const int* in_sizes, int n_in,
                              void* d_out, int out_size, void* d_ws, size_t ws_size,
                              hipStream_t stream) {
  const float* x     = (const float*)d_in[0];
  const float* W     = (const float*)d_in[1];
  const float* codes = (const float*)d_in[2];
  const int* labels  = (const int*)d_in[3];
  const int* Kp      = (const int*)d_in[4];

  const int B = out_size / NCLS;             // 256
  const int N = in_sizes[3];                 // 100000
  const int D = in_sizes[0] / B;             // 2048
  const int Npad = (N + 255) & ~255;         // 100096
  const int cpb = (((N + NCHX - 1) / NCHX) + 127) & ~127;  // 1664 (mult of 128)
  const int nCvt = Npad / 256;               // 391 cvt blocks (256 rows each)

  // ws layout; nothing needs host-side init (all state written before read).
  char* p = (char*)d_ws;
  double* out64      = (double*)p;   p += (size_t)B * 64 * sizeof(double);       // 128 KB
  unsigned short* out16 = (unsigned short*)p; p += (size_t)B * 64 * 2;           // 32 KB
  double* B1sq       = (double*)p;   p += (size_t)B * sizeof(double);            // 2 KB
  int* shiftp        = (int*)p;      p += 64;
  float* cmaxSlab    = (float*)p;    p += 4096;                                  // nCvt floats
  unsigned short* histg = (unsigned short*)p; p += (size_t)NCHX * B * NBK * 2;   // 8 MB
  unsigned char* buck   = (unsigned char*)p;  p += (size_t)B * N;                // 25.6 MB
  unsigned short* codes16 = (unsigned short*)p;                                  // 12.8 MB

  k_prep<<<nCvt + B + 1, 1024, 0, stream>>>(x, W, codes, labels, N, Npad, D, B, nCvt,
                                            codes16, cmaxSlab, out64, out16, B1sq, shiftp);
  k_mhist<<<dim3(NCHX, B / MROWS), 512, 0, stream>>>(codes16, out16, B1sq, cmaxSlab,
                                                     nCvt, N, Npad, cpb, B, histg, buck);
  k_rowfinal<<<B, 1024, 0, stream>>>(codes, out64, B1sq, cmaxSlab, histg, buck,
                                     labels, shiftp, Kp, (float*)d_out, nCvt, N, B);
}